// Round 1
// baseline (320.035 us; speedup 1.0000x reference)
//
#include <hip/hip_runtime.h>
#include <math.h>

#define NG 8
#define SEQ 4096
#define DM 1024
#define NE 64
#define GS (NG * SEQ)          // 32768 tokens
#define KSEL 1024              // expert capacity
#define MASK_ELEMS (NE * GS)   // 2097152

// ws layout:
//   [0, MASK_ELEMS*4)                 probsT  float[NE][GS]  (expert-major)
//   [MASK_ELEMS*4, +256)              thr     u32[NE]   (threshold key per expert)
//   [.. +256)                         cut     i32[NE]   (max tied token index selected)

// ---------------- Kernel 1: logits GEMM (fp64 acc) + softmax, transposed store ----
__global__ __launch_bounds__(256)
void k_gemm_softmax(const float* __restrict__ x, const float* __restrict__ w,
                    const float* __restrict__ bias, const float* __restrict__ temp,
                    float* __restrict__ probsT) {
  __shared__ float As[32][68];   // As[kk][token_local], padded: conflict-free b128 reads
  __shared__ float Bs[32][64];   // Bs[kk][expert]
  __shared__ float Pt[64][68];   // staging: Pt[expert][token_local]

  const int tid = threadIdx.x;
  const int tx = tid & 15, ty = tid >> 4;   // thread computes tokens ty*4..+3, experts tx*4..+3
  const int m0 = blockIdx.x * 64;

  double acc[4][4];
#pragma unroll
  for (int i = 0; i < 4; ++i)
#pragma unroll
    for (int j = 0; j < 4; ++j) acc[i][j] = 0.0;

  for (int k0 = 0; k0 < DM; k0 += 32) {
    // stage A tile (64 tokens x 32 d), transposed into As[kk][tok]
#pragma unroll
    for (int rr = 0; rr < 2; ++rr) {
      int idx = tid + rr * 256;
      int row = idx >> 3;      // token_local 0..63
      int f4  = idx & 7;       // float4 index along d
      float4 v = *(const float4*)(x + (size_t)(m0 + row) * DM + k0 + f4 * 4);
      As[f4 * 4 + 0][row] = v.x;
      As[f4 * 4 + 1][row] = v.y;
      As[f4 * 4 + 2][row] = v.z;
      As[f4 * 4 + 3][row] = v.w;
    }
    // stage B tile (32 d x 64 experts), row-major direct
#pragma unroll
    for (int rr = 0; rr < 2; ++rr) {
      int idx = tid + rr * 256;
      int row = idx >> 4;      // kk 0..31
      int f4  = idx & 15;
      *(float4*)(&Bs[row][f4 * 4]) =
          *(const float4*)(w + (size_t)(k0 + row) * NE + f4 * 4);
    }
    __syncthreads();
#pragma unroll
    for (int kk = 0; kk < 32; ++kk) {
      float4 av = *(const float4*)(&As[kk][ty * 4]);
      float4 bv = *(const float4*)(&Bs[kk][tx * 4]);
      double a0 = av.x, a1 = av.y, a2 = av.z, a3 = av.w;
      double b0 = bv.x, b1 = bv.y, b2 = bv.z, b3 = bv.w;
      acc[0][0] += a0 * b0; acc[0][1] += a0 * b1; acc[0][2] += a0 * b2; acc[0][3] += a0 * b3;
      acc[1][0] += a1 * b0; acc[1][1] += a1 * b1; acc[1][2] += a1 * b2; acc[1][3] += a1 * b3;
      acc[2][0] += a2 * b0; acc[2][1] += a2 * b1; acc[2][2] += a2 * b2; acc[2][3] += a2 * b3;
      acc[3][0] += a3 * b0; acc[3][1] += a3 * b1; acc[3][2] += a3 * b2; acc[3][3] += a3 * b3;
    }
    __syncthreads();
  }

  // bias + temperature + softmax (fp64 throughout; rounds to fp32 at the end)
  double st = (double)temp[0];
  if (st < 0.1) st = 0.1;
  const double inv_t = 1.0 / st;
  float b4[4];
#pragma unroll
  for (int j = 0; j < 4; ++j) b4[j] = bias[tx * 4 + j];

#pragma unroll
  for (int i = 0; i < 4; ++i) {
    double l[4];
#pragma unroll
    for (int j = 0; j < 4; ++j) l[j] = (acc[i][j] + (double)b4[j]) * inv_t;
    double m = l[0];
#pragma unroll
    for (int j = 1; j < 4; ++j) m = fmax(m, l[j]);
    // reduce across the 16 lanes sharing this token row (xor masks stay in-group)
#pragma unroll
    for (int off = 1; off < 16; off <<= 1) m = fmax(m, __shfl_xor(m, off));
    double p[4], s = 0.0;
#pragma unroll
    for (int j = 0; j < 4; ++j) { p[j] = exp(l[j] - m); s += p[j]; }
#pragma unroll
    for (int off = 1; off < 16; off <<= 1) s += __shfl_xor(s, off);
    const double invs = 1.0 / s;
#pragma unroll
    for (int j = 0; j < 4; ++j)
      Pt[tx * 4 + j][ty * 4 + i] = (float)(p[j] * invs);
  }
  __syncthreads();

  // coalesced transposed write: probsT[e][m0 + t]
  const int e = tid >> 2, q = tid & 3;
#pragma unroll
  for (int c2 = 0; c2 < 4; ++c2) {
    *(float4*)(probsT + (size_t)e * GS + m0 + q * 16 + c2 * 4) =
        *(const float4*)(&Pt[e][q * 16 + c2 * 4]);
  }
}

// ---------------- Kernel 2: per-expert exact k-th largest via 4-pass radix select --
__global__ __launch_bounds__(256)
void k_select(const float* __restrict__ probsT, unsigned* __restrict__ thr,
              int* __restrict__ cut) {
  const int e = blockIdx.x;
  const int tid = threadIdx.x;
  const int wv = tid >> 6;
  const float* col = probsT + (size_t)e * GS;

  __shared__ unsigned hist[4][256];  // per-wave sub-histograms
  __shared__ unsigned sh_pfx, sh_r;
  __shared__ unsigned lcnt;
  __shared__ int lidx[256];

  if (tid == 0) { sh_pfx = 0u; sh_r = KSEL; lcnt = 0u; }
  __syncthreads();

  for (int pass = 0; pass < 4; ++pass) {
    const int shift = 24 - 8 * pass;
    for (int i = tid; i < 1024; i += 256) ((unsigned*)hist)[i] = 0u;
    __syncthreads();
    const unsigned pfx = sh_pfx;
    const unsigned hm = (pass == 0) ? 0u : (0xFFFFFFFFu << (shift + 8));
    for (int t = tid; t < GS; t += 256) {
      unsigned key = __float_as_uint(col[t]);
      if ((key & hm) == (pfx & hm))
        atomicAdd(&hist[wv][(key >> shift) & 255], 1u);
    }
    __syncthreads();
    if (tid == 0) {
      unsigned r = sh_r, cum = 0;
      int chosen = 0;
      for (int b = 255; b >= 0; --b) {
        unsigned c = hist[0][b] + hist[1][b] + hist[2][b] + hist[3][b];
        if (cum + c >= r) { chosen = b; sh_r = r - cum; break; }
        cum += c;
      }
      sh_pfx = pfx | ((unsigned)chosen << shift);
    }
    __syncthreads();
  }

  const unsigned T = sh_pfx;
  const unsigned r = sh_r;  // take the r lowest-index tokens among key==T

  for (int t = tid; t < GS; t += 256) {
    if (__float_as_uint(col[t]) == T) {
      unsigned p = atomicAdd(&lcnt, 1u);
      if (p < 256u) lidx[p] = t;
    }
  }
  __syncthreads();
  if (tid == 0) {
    int m = (int)(lcnt < 256u ? lcnt : 256u);
    for (int i = 1; i < m; ++i) {          // tiny insertion sort (m is ~1 in practice)
      int v = lidx[i], j = i - 1;
      while (j >= 0 && lidx[j] > v) { lidx[j + 1] = lidx[j]; --j; }
      lidx[j + 1] = v;
    }
    cut[e] = (r <= (unsigned)m) ? lidx[r - 1] : 0x7FFFFFFF;
    thr[e] = T;
  }
}

// ---------------- Kernel 3: dense mask scatter + loss -----------------------------
__global__ __launch_bounds__(256)
void k_scatter(const float* __restrict__ probsT, const unsigned* __restrict__ thr,
               const int* __restrict__ cut, float* __restrict__ out) {
  const int gid = blockIdx.x * 256 + threadIdx.x;
  const int base = gid * 4;
  const int e = base >> 15;          // /GS
  const int t = base & (GS - 1);
  float4 p = *(const float4*)(probsT + (size_t)base);
  const unsigned T = thr[e];
  const int ct = cut[e];
  float pv[4] = {p.x, p.y, p.z, p.w};
  float mk[4], wt[4];
#pragma unroll
  for (int c = 0; c < 4; ++c) {
    unsigned key = __float_as_uint(pv[c]);
    bool sel = (key > T) || (key == T && (t + c) <= ct);
    mk[c] = sel ? 1.0f : 0.0f;
    wt[c] = sel ? pv[c] : 0.0f;
  }
  *(float4*)(out + (size_t)base) = make_float4(mk[0], mk[1], mk[2], mk[3]);
  *(float4*)(out + (size_t)MASK_ELEMS + base) = make_float4(wt[0], wt[1], wt[2], wt[3]);
  if (gid == 0) out[2 * (size_t)MASK_ELEMS] = 0.0f;
}

extern "C" void kernel_launch(void* const* d_in, const int* in_sizes, int n_in,
                              void* d_out, int out_size, void* d_ws, size_t ws_size,
                              hipStream_t stream) {
  const float* x    = (const float*)d_in[0];
  const float* gw   = (const float*)d_in[1];
  const float* gb   = (const float*)d_in[2];
  const float* temp = (const float*)d_in[3];
  // d_in[4] = expert_capacity (=1024, compile-time constant here)

  float* probsT = (float*)d_ws;
  unsigned* thr = (unsigned*)((char*)d_ws + (size_t)MASK_ELEMS * 4);
  int* cut      = (int*)(thr + NE);

  k_gemm_softmax<<<GS / 64, 256, 0, stream>>>(x, gw, gb, temp, probsT);
  k_select<<<NE, 256, 0, stream>>>(probsT, thr, cut);
  k_scatter<<<MASK_ELEMS / 1024, 256, 0, stream>>>(probsT, thr, cut, (float*)d_out);
}

// Round 2
// 152.269 us; speedup vs baseline: 2.1018x; 2.1018x over previous
//
#include <hip/hip_runtime.h>
#include <math.h>

#define NG 8
#define SEQ 4096
#define DM 1024
#define NE 64
#define GS (NG * SEQ)          // 32768 tokens
#define KSEL 1024              // expert capacity
#define MASK_ELEMS (NE * GS)   // 2097152
#define SEG 16                 // blocks per expert for column-scan kernels
#define SEGLEN (GS / SEG)      // 2048 tokens per block

// ws layout (bytes):
//   [0, 8388608)        probsT   float[NE][GS] (expert-major)
//   [+0, +262144)       ghist    u32[4][NE][256]  per-pass global histograms
//   [+262144, +256)     tiecnt   u32[NE]
//   [..,+512)           state    uint2[NE]  {threshold key, remaining rank r}
//   [..,+256)           cut      i32[NE]    (max tied token index selected)
//   [..,+262144)        tiebuf   i32[NE][1024]

// ---------------- Kernel 1: logits GEMM (fp64 acc) + softmax (fp32 tail) ---------
__global__ __launch_bounds__(256)
void k_gemm_softmax(const float* __restrict__ x, const float* __restrict__ w,
                    const float* __restrict__ bias, const float* __restrict__ temp,
                    float* __restrict__ probsT) {
  __shared__ float As[32][68];
  __shared__ float Bs[32][64];
  __shared__ float Pt[64][68];

  const int tid = threadIdx.x;
  const int tx = tid & 15, ty = tid >> 4;
  const int m0 = blockIdx.x * 64;

  double acc[4][4];
#pragma unroll
  for (int i = 0; i < 4; ++i)
#pragma unroll
    for (int j = 0; j < 4; ++j) acc[i][j] = 0.0;

  for (int k0 = 0; k0 < DM; k0 += 32) {
#pragma unroll
    for (int rr = 0; rr < 2; ++rr) {
      int idx = tid + rr * 256;
      int row = idx >> 3;
      int f4  = idx & 7;
      float4 v = *(const float4*)(x + (size_t)(m0 + row) * DM + k0 + f4 * 4);
      As[f4 * 4 + 0][row] = v.x;
      As[f4 * 4 + 1][row] = v.y;
      As[f4 * 4 + 2][row] = v.z;
      As[f4 * 4 + 3][row] = v.w;
    }
#pragma unroll
    for (int rr = 0; rr < 2; ++rr) {
      int idx = tid + rr * 256;
      int row = idx >> 4;
      int f4  = idx & 15;
      *(float4*)(&Bs[row][f4 * 4]) =
          *(const float4*)(w + (size_t)(k0 + row) * NE + f4 * 4);
    }
    __syncthreads();
#pragma unroll
    for (int kk = 0; kk < 32; ++kk) {
      float4 av = *(const float4*)(&As[kk][ty * 4]);
      float4 bv = *(const float4*)(&Bs[kk][tx * 4]);
      double a0 = av.x, a1 = av.y, a2 = av.z, a3 = av.w;
      double b0 = bv.x, b1 = bv.y, b2 = bv.z, b3 = bv.w;
      acc[0][0] += a0 * b0; acc[0][1] += a0 * b1; acc[0][2] += a0 * b2; acc[0][3] += a0 * b3;
      acc[1][0] += a1 * b0; acc[1][1] += a1 * b1; acc[1][2] += a1 * b2; acc[1][3] += a1 * b3;
      acc[2][0] += a2 * b0; acc[2][1] += a2 * b1; acc[2][2] += a2 * b2; acc[2][3] += a2 * b3;
      acc[3][0] += a3 * b0; acc[3][1] += a3 * b1; acc[3][2] += a3 * b2; acc[3][3] += a3 * b3;
    }
    __syncthreads();
  }

  // bias + temperature in fp64 (ranking anchor), exp/sum/div in fp32.
  double st = (double)temp[0];
  if (st < 0.1) st = 0.1;
  const double inv_t = 1.0 / st;
  float b4[4];
#pragma unroll
  for (int j = 0; j < 4; ++j) b4[j] = bias[tx * 4 + j];

#pragma unroll
  for (int i = 0; i < 4; ++i) {
    double l[4];
#pragma unroll
    for (int j = 0; j < 4; ++j) l[j] = (acc[i][j] + (double)b4[j]) * inv_t;
    double m = fmax(fmax(l[0], l[1]), fmax(l[2], l[3]));
#pragma unroll
    for (int off = 1; off < 16; off <<= 1) m = fmax(m, __shfl_xor(m, off));
    float p[4], s = 0.0f;
#pragma unroll
    for (int j = 0; j < 4; ++j) { p[j] = __expf((float)(l[j] - m)); s += p[j]; }
#pragma unroll
    for (int off = 1; off < 16; off <<= 1) s += __shfl_xor(s, off);
    const float invs = 1.0f / s;
#pragma unroll
    for (int j = 0; j < 4; ++j)
      Pt[tx * 4 + j][ty * 4 + i] = p[j] * invs;
  }
  __syncthreads();

  const int e = tid >> 2, q = tid & 3;
#pragma unroll
  for (int c2 = 0; c2 < 4; ++c2) {
    *(float4*)(probsT + (size_t)e * GS + m0 + q * 16 + c2 * 4) =
        *(const float4*)(&Pt[e][q * 16 + c2 * 4]);
  }
}

// ------------- cooperative bucket pick from a 256-bin histogram (block-wide) ------
// bins: global per-expert histogram. Finds bucket b s.t. suffix_sum(b) >= r_in
// and suffix_sum(b+1) < r_in; r_out = r_in - suffix_sum(b+1).
__device__ __forceinline__ void pick_scan(const unsigned* __restrict__ bins,
                                          unsigned r_in, unsigned& bucket,
                                          unsigned& r_out, unsigned* res) {
  __syncthreads();  // protect res[] from readers of a previous pick_scan
  const int tid = threadIdx.x;
  if (tid < 64) {
    uint4 b = ((const uint4*)bins)[tid];
    unsigned s3 = b.w, s2 = b.z + s3, s1 = b.y + s2, s0 = b.x + s1;
    unsigned suf = s0;
#pragma unroll
    for (int off = 1; off < 64; off <<= 1) {
      unsigned t = __shfl_down(suf, off);
      if (tid + off < 64) suf += t;
    }
    unsigned above = suf - s0;  // strictly above this quad
    unsigned inc0 = above + s0, inc1 = above + s1, inc2 = above + s2, inc3 = above + s3;
    if (inc3 >= r_in && inc3 - b.w < r_in) { res[0] = 4 * tid + 3; res[1] = r_in - (inc3 - b.w); }
    if (inc2 >= r_in && inc2 - b.z < r_in) { res[0] = 4 * tid + 2; res[1] = r_in - (inc2 - b.z); }
    if (inc1 >= r_in && inc1 - b.y < r_in) { res[0] = 4 * tid + 1; res[1] = r_in - (inc1 - b.y); }
    if (inc0 >= r_in && inc0 - b.x < r_in) { res[0] = 4 * tid + 0; res[1] = r_in - (inc0 - b.x); }
  }
  __syncthreads();
  bucket = res[0];
  r_out = res[1];
}

// ---------------- Kernel 2: radix-select histogram pass (parallel, 1024 blocks) ---
template <int PASS>
__global__ __launch_bounds__(256)
void k_hist(const float* __restrict__ probsT, unsigned* __restrict__ ghist) {
  __shared__ unsigned h[4][256];
  __shared__ unsigned res[2];
  const int tid = threadIdx.x, wv = tid >> 6;
  const int e = blockIdx.x >> 4;
  const int seg = blockIdx.x & (SEG - 1);
  h[0][tid] = 0; h[1][tid] = 0; h[2][tid] = 0; h[3][tid] = 0;

  unsigned pfx = 0, r = KSEL;
#pragma unroll
  for (int p = 0; p < PASS; ++p) {
    unsigned b, rn;
    pick_scan(ghist + ((size_t)p * NE + e) * 256, r, b, rn, res);
    pfx |= b << (24 - 8 * p);
    r = rn;
  }
  __syncthreads();

  const unsigned hm = PASS ? (0xFFFFFFFFu << (32 - 8 * PASS)) : 0u;
  const int shift = 24 - 8 * PASS;
  const float4* col = (const float4*)(probsT + (size_t)e * GS + seg * SEGLEN);
#pragma unroll
  for (int i = 0; i < SEGLEN / 1024; ++i) {
    float4 v = col[i * 256 + tid];
    unsigned k0 = __float_as_uint(v.x), k1 = __float_as_uint(v.y);
    unsigned k2 = __float_as_uint(v.z), k3 = __float_as_uint(v.w);
    if (PASS == 0 || (k0 & hm) == pfx) atomicAdd(&h[wv][(k0 >> shift) & 255], 1u);
    if (PASS == 0 || (k1 & hm) == pfx) atomicAdd(&h[wv][(k1 >> shift) & 255], 1u);
    if (PASS == 0 || (k2 & hm) == pfx) atomicAdd(&h[wv][(k2 >> shift) & 255], 1u);
    if (PASS == 0 || (k3 & hm) == pfx) atomicAdd(&h[wv][(k3 >> shift) & 255], 1u);
  }
  __syncthreads();
  unsigned c = h[0][tid] + h[1][tid] + h[2][tid] + h[3][tid];
  if (c) atomicAdd(&ghist[((size_t)PASS * NE + e) * 256 + tid], c);
}

// ---------------- Kernel 3: tie collection (+ final pick, writes state) -----------
__global__ __launch_bounds__(256)
void k_ties(const float* __restrict__ probsT, const unsigned* __restrict__ ghist,
            uint2* __restrict__ state, unsigned* __restrict__ tiecnt,
            int* __restrict__ tiebuf) {
  __shared__ unsigned res[2];
  const int tid = threadIdx.x;
  const int e = blockIdx.x >> 4;
  const int seg = blockIdx.x & (SEG - 1);

  unsigned pfx = 0, r = KSEL;
#pragma unroll
  for (int p = 0; p < 4; ++p) {
    unsigned b, rn;
    pick_scan(ghist + ((size_t)p * NE + e) * 256, r, b, rn, res);
    pfx |= b << (24 - 8 * p);
    r = rn;
  }
  if (tid == 0 && seg == 0) state[e] = make_uint2(pfx, r);

  const float* col = probsT + (size_t)e * GS + seg * SEGLEN;
  for (int i = 0; i < SEGLEN / 256; ++i) {
    int t = i * 256 + tid;
    if (__float_as_uint(col[t]) == pfx) {
      unsigned p = atomicAdd(&tiecnt[e], 1u);
      if (p < 1024u) tiebuf[e * 1024 + p] = seg * SEGLEN + t;
    }
  }
}

// ---------------- Kernel 4: cut index = r-th smallest tie index -------------------
__global__ __launch_bounds__(256)
void k_cut(const uint2* __restrict__ state, const unsigned* __restrict__ tiecnt,
           const int* __restrict__ tiebuf, int* __restrict__ cut) {
  __shared__ int sl[1024];
  const int e = blockIdx.x, tid = threadIdx.x;
  const int cnt = (int)min(tiecnt[e], 1024u);
  const int r = (int)state[e].y;
  for (int i = tid; i < cnt; i += 256) sl[i] = tiebuf[e * 1024 + i];
  __syncthreads();
  if (r > cnt) { if (tid == 0) cut[e] = 0x7FFFFFFF; return; }
  for (int i = tid; i < cnt; i += 256) {
    int v = sl[i], rank = 0;
    for (int j = 0; j < cnt; ++j) rank += (sl[j] < v);
    if (rank == r - 1) cut[e] = v;
  }
}

// ---------------- Kernel 5: dense mask scatter + loss -----------------------------
__global__ __launch_bounds__(256)
void k_scatter(const float* __restrict__ probsT, const uint2* __restrict__ state,
               const int* __restrict__ cut, float* __restrict__ out) {
  const int gid = blockIdx.x * 256 + threadIdx.x;
  const int base = gid * 4;
  const int e = base >> 15;
  const int t = base & (GS - 1);
  float4 p = *(const float4*)(probsT + (size_t)base);
  const unsigned T = state[e].x;
  const int ct = cut[e];
  float pv[4] = {p.x, p.y, p.z, p.w};
  float mk[4], wt[4];
#pragma unroll
  for (int c = 0; c < 4; ++c) {
    unsigned key = __float_as_uint(pv[c]);
    bool sel = (key > T) || (key == T && (t + c) <= ct);
    mk[c] = sel ? 1.0f : 0.0f;
    wt[c] = sel ? pv[c] : 0.0f;
  }
  *(float4*)(out + (size_t)base) = make_float4(mk[0], mk[1], mk[2], mk[3]);
  *(float4*)(out + (size_t)MASK_ELEMS + base) = make_float4(wt[0], wt[1], wt[2], wt[3]);
  if (gid == 0) out[2 * (size_t)MASK_ELEMS] = 0.0f;
}

extern "C" void kernel_launch(void* const* d_in, const int* in_sizes, int n_in,
                              void* d_out, int out_size, void* d_ws, size_t ws_size,
                              hipStream_t stream) {
  const float* x    = (const float*)d_in[0];
  const float* gw   = (const float*)d_in[1];
  const float* gb   = (const float*)d_in[2];
  const float* temp = (const float*)d_in[3];

  float* probsT    = (float*)d_ws;
  unsigned* ghist  = (unsigned*)((char*)d_ws + (size_t)MASK_ELEMS * 4);
  unsigned* tiecnt = ghist + 4 * NE * 256;
  uint2* state     = (uint2*)(tiecnt + NE);
  int* cutp        = (int*)(state + NE);
  int* tiebuf      = cutp + NE;

  hipMemsetAsync(ghist, 0, (4 * NE * 256 + NE) * sizeof(unsigned), stream);
  k_gemm_softmax<<<GS / 64, 256, 0, stream>>>(x, gw, gb, temp, probsT);
  k_hist<0><<<NE * SEG, 256, 0, stream>>>(probsT, ghist);
  k_hist<1><<<NE * SEG, 256, 0, stream>>>(probsT, ghist);
  k_hist<2><<<NE * SEG, 256, 0, stream>>>(probsT, ghist);
  k_hist<3><<<NE * SEG, 256, 0, stream>>>(probsT, ghist);
  k_ties<<<NE * SEG, 256, 0, stream>>>(probsT, ghist, state, tiecnt, tiebuf);
  k_cut<<<NE, 256, 0, stream>>>(state, tiecnt, tiebuf, cutp);
  k_scatter<<<MASK_ELEMS / 1024, 256, 0, stream>>>(probsT, state, cutp, (float*)d_out);
}

// Round 4
// 116.706 us; speedup vs baseline: 2.7422x; 1.3047x over previous
//
#include <hip/hip_runtime.h>
#include <math.h>

#define NG 8
#define SEQ 4096
#define DM 1024
#define NE 64
#define GS (NG * SEQ)          // 32768 tokens
#define KSEL 1024              // expert capacity
#define MASK_ELEMS (NE * GS)   // 2097152
#define SEG 16
#define SEGLEN (GS / SEG)

typedef __attribute__((ext_vector_type(4))) double f64x4;

// ---------------- Kernel 1: fp64 GEMM (MFMA w/ self-calibrated layout, VALU
// fallback) + canonical-LDS softmax ------------------------------------------------
__global__ __launch_bounds__(256)
void k_gemm_softmax(const float* __restrict__ x, const float* __restrict__ w,
                    const float* __restrict__ bias, const float* __restrict__ temp,
                    float* __restrict__ probsT) {
  __shared__ double S[8192];                       // 64 KB, manually partitioned
  double (*As)[64] = (double (*)[64])(S);          // [k][row^swz]   32 KB
  double (*Bs)[64] = (double (*)[64])(S + 4096);   // [k][expert]    32 KB
  double (*Lt)[65] = (double (*)[65])(S);          // canonical logits (reuses As)
  float  (*Pt)[68] = (float  (*)[68])(S + 4224);   // transpose staging (after Lt)

  const int tid = threadIdx.x;
  const int wid = tid >> 6, lane = tid & 63;
  const int lrow = lane & 15;
  const int lk = lane >> 4;
  const int m0 = blockIdx.x * 64;
  const int rw = wid * 16 + lrow;
  const int tx4 = (tid & 15) * 4, ty4 = (tid >> 4) * 4;  // VALU-fallback tile

  // --- self-calibration probes: measure D(lane,reg)->(i,j), verify A/B k-split ---
  int irow[4], jcol[4];
  bool okl = true;
  {
    f64x4 z4 = {0.0, 0.0, 0.0, 0.0};
    double alow = (double)lrow, ahigh = (double)lk;
    f64x4 p1 = __builtin_amdgcn_mfma_f64_16x16x4f64(alow, 1.0, z4, 0, 0, 0);
    f64x4 p2 = __builtin_amdgcn_mfma_f64_16x16x4f64(1.0, alow, z4, 0, 0, 0);
    f64x4 p3 = __builtin_amdgcn_mfma_f64_16x16x4f64(ahigh, 1.0, z4, 0, 0, 0);
    f64x4 p4 = __builtin_amdgcn_mfma_f64_16x16x4f64(1.0, ahigh, z4, 0, 0, 0);
#pragma unroll
    for (int b = 0; b < 4; ++b) {
      int i = ((int)p1[b]) >> 2;
      int j = ((int)p2[b]) >> 2;
      irow[b] = i; jcol[b] = j;
      okl = okl && (p1[b] == (double)(4 * i)) && (i >= 0) && (i < 16);
      okl = okl && (p2[b] == (double)(4 * j)) && (j >= 0) && (j < 16);
      okl = okl && (p3[b] == 6.0) && (p4[b] == 6.0);
    }
  }
  const bool use_mfma = (__all(okl ? 1 : 0) != 0);   // block-uniform

  f64x4 acc[4];
#pragma unroll
  for (int cb = 0; cb < 4; ++cb) acc[cb] = (f64x4){0.0, 0.0, 0.0, 0.0};
  double acc2[4][4];
#pragma unroll
  for (int i = 0; i < 4; ++i)
#pragma unroll
    for (int j = 0; j < 4; ++j) acc2[i][j] = 0.0;

  for (int t = 0; t < 16; ++t) {
    const int k0 = t * 64;
    // stage A: f32 coalesced load -> f64, transposed + XOR-swizzled
#pragma unroll
    for (int rr = 0; rr < 4; ++rr) {
      int idx = tid + rr * 256;
      int row = idx >> 4, f4 = idx & 15;
      float4 v = *(const float4*)(x + (size_t)(m0 + row) * DM + k0 + f4 * 4);
#pragma unroll
      for (int j = 0; j < 4; ++j) {
        int kl = f4 * 4 + j;
        As[kl][row ^ (kl >> 3)] = (double)((const float*)&v)[j];
      }
    }
    // stage B
#pragma unroll
    for (int rr = 0; rr < 4; ++rr) {
      int idx = tid + rr * 256;
      int kr = idx >> 4, eq = idx & 15;
      float4 v = *(const float4*)(w + (size_t)(k0 + kr) * NE + eq * 4);
#pragma unroll
      for (int j = 0; j < 4; ++j) Bs[kr][eq * 4 + j] = (double)((const float*)&v)[j];
    }
    __syncthreads();

    if (use_mfma) {
#pragma unroll
      for (int kc = 0; kc < 16; ++kc) {
        const int kb = kc * 4 + lk;
        double a = As[kb][rw ^ (kb >> 3)];
        double b0 = Bs[kb][lrow];
        double b1 = Bs[kb][16 + lrow];
        double b2 = Bs[kb][32 + lrow];
        double b3 = Bs[kb][48 + lrow];
        acc[0] = __builtin_amdgcn_mfma_f64_16x16x4f64(a, b0, acc[0], 0, 0, 0);
        acc[1] = __builtin_amdgcn_mfma_f64_16x16x4f64(a, b1, acc[1], 0, 0, 0);
        acc[2] = __builtin_amdgcn_mfma_f64_16x16x4f64(a, b2, acc[2], 0, 0, 0);
        acc[3] = __builtin_amdgcn_mfma_f64_16x16x4f64(a, b3, acc[3], 0, 0, 0);
      }
    } else {
      // verified round-2 VALU microkernel (correctness fallback)
#pragma unroll 8
      for (int kk = 0; kk < 64; ++kk) {
        const int sw = kk >> 3;
        double a0 = As[kk][(ty4 + 0) ^ sw];
        double a1 = As[kk][(ty4 + 1) ^ sw];
        double a2 = As[kk][(ty4 + 2) ^ sw];
        double a3 = As[kk][(ty4 + 3) ^ sw];
        double b0 = Bs[kk][tx4 + 0];
        double b1 = Bs[kk][tx4 + 1];
        double b2 = Bs[kk][tx4 + 2];
        double b3 = Bs[kk][tx4 + 3];
        acc2[0][0] += a0 * b0; acc2[0][1] += a0 * b1; acc2[0][2] += a0 * b2; acc2[0][3] += a0 * b3;
        acc2[1][0] += a1 * b0; acc2[1][1] += a1 * b1; acc2[1][2] += a1 * b2; acc2[1][3] += a1 * b3;
        acc2[2][0] += a2 * b0; acc2[2][1] += a2 * b1; acc2[2][2] += a2 * b2; acc2[2][3] += a2 * b3;
        acc2[3][0] += a3 * b0; acc2[3][1] += a3 * b1; acc2[3][2] += a3 * b2; acc2[3][3] += a3 * b3;
      }
    }
    __syncthreads();
  }

  // --- write raw dots into canonical Lt[token_local][expert] (overlays As) ---
  if (use_mfma) {
#pragma unroll
    for (int cb = 0; cb < 4; ++cb)
#pragma unroll
      for (int b = 0; b < 4; ++b)
        Lt[wid * 16 + irow[b]][cb * 16 + jcol[b]] = acc[cb][b];
  } else {
#pragma unroll
    for (int i = 0; i < 4; ++i)
#pragma unroll
      for (int j = 0; j < 4; ++j)
        Lt[ty4 + i][tx4 + j] = acc2[i][j];
  }
  __syncthreads();

  // --- phase 2: softmax from canonical layout (fp64 logits, fp32 tail) ---
  {
    double st = (double)temp[0];
    if (st < 0.1) st = 0.1;
    const double inv_t = 1.0 / st;
    const int tt = tid >> 2, q = tid & 3;   // token tt, experts q*16..q*16+15
    double l[16];
    double mx = -1.0e300;
#pragma unroll
    for (int j = 0; j < 16; ++j) {
      l[j] = (Lt[tt][q * 16 + j] + (double)bias[q * 16 + j]) * inv_t;
      mx = fmax(mx, l[j]);
    }
    mx = fmax(mx, __shfl_xor(mx, 1));
    mx = fmax(mx, __shfl_xor(mx, 2));
    float p[16], s = 0.0f;
#pragma unroll
    for (int j = 0; j < 16; ++j) { p[j] = __expf((float)(l[j] - mx)); s += p[j]; }
    s += __shfl_xor(s, 1);
    s += __shfl_xor(s, 2);
    const float invs = 1.0f / s;
    __syncthreads();   // everyone done reading Lt before Pt overlays nothing, but keep order strict
#pragma unroll
    for (int j = 0; j < 16; ++j) Pt[q * 16 + j][tt] = p[j] * invs;
  }
  __syncthreads();

  // --- phase 3: coalesced expert-major store ---
  {
    const int e = tid >> 2, q = tid & 3;
#pragma unroll
    for (int c2 = 0; c2 < 4; ++c2) {
      *(float4*)(probsT + (size_t)e * GS + m0 + q * 16 + c2 * 4) =
          *(const float4*)(&Pt[e][q * 16 + c2 * 4]);
    }
  }
}

// ------------- cooperative bucket pick from a 256-bin histogram (block-wide) ------
__device__ __forceinline__ void pick_scan(const unsigned* __restrict__ bins,
                                          unsigned r_in, unsigned& bucket,
                                          unsigned& r_out, unsigned* res) {
  __syncthreads();
  const int tid = threadIdx.x;
  if (tid < 64) {
    uint4 b = ((const uint4*)bins)[tid];
    unsigned s3 = b.w, s2 = b.z + s3, s1 = b.y + s2, s0 = b.x + s1;
    unsigned suf = s0;
#pragma unroll
    for (int off = 1; off < 64; off <<= 1) {
      unsigned t = __shfl_down(suf, off);
      if (tid + off < 64) suf += t;
    }
    unsigned above = suf - s0;
    unsigned inc0 = above + s0, inc1 = above + s1, inc2 = above + s2, inc3 = above + s3;
    if (inc3 >= r_in && inc3 - b.w < r_in) { res[0] = 4 * tid + 3; res[1] = r_in - (inc3 - b.w); }
    if (inc2 >= r_in && inc2 - b.z < r_in) { res[0] = 4 * tid + 2; res[1] = r_in - (inc2 - b.z); }
    if (inc1 >= r_in && inc1 - b.y < r_in) { res[0] = 4 * tid + 1; res[1] = r_in - (inc1 - b.y); }
    if (inc0 >= r_in && inc0 - b.x < r_in) { res[0] = 4 * tid + 0; res[1] = r_in - (inc0 - b.x); }
  }
  __syncthreads();
  bucket = res[0];
  r_out = res[1];
}

// ---------------- Kernel 2: radix-select histogram pass (parallel, 1024 blocks) ---
template <int PASS>
__global__ __launch_bounds__(256)
void k_hist(const float* __restrict__ probsT, unsigned* __restrict__ ghist) {
  __shared__ unsigned h[4][256];
  __shared__ unsigned res[2];
  const int tid = threadIdx.x, wv = tid >> 6;
  const int e = blockIdx.x >> 4;
  const int seg = blockIdx.x & (SEG - 1);
  h[0][tid] = 0; h[1][tid] = 0; h[2][tid] = 0; h[3][tid] = 0;

  unsigned pfx = 0, r = KSEL;
#pragma unroll
  for (int p = 0; p < PASS; ++p) {
    unsigned b, rn;
    pick_scan(ghist + ((size_t)p * NE + e) * 256, r, b, rn, res);
    pfx |= b << (24 - 8 * p);
    r = rn;
  }
  __syncthreads();

  const unsigned hm = PASS ? (0xFFFFFFFFu << (32 - 8 * PASS)) : 0u;
  const int shift = 24 - 8 * PASS;
  const float4* col = (const float4*)(probsT + (size_t)e * GS + seg * SEGLEN);
#pragma unroll
  for (int i = 0; i < SEGLEN / 1024; ++i) {
    float4 v = col[i * 256 + tid];
    unsigned k0 = __float_as_uint(v.x), k1 = __float_as_uint(v.y);
    unsigned k2 = __float_as_uint(v.z), k3 = __float_as_uint(v.w);
    if (PASS == 0 || (k0 & hm) == pfx) atomicAdd(&h[wv][(k0 >> shift) & 255], 1u);
    if (PASS == 0 || (k1 & hm) == pfx) atomicAdd(&h[wv][(k1 >> shift) & 255], 1u);
    if (PASS == 0 || (k2 & hm) == pfx) atomicAdd(&h[wv][(k2 >> shift) & 255], 1u);
    if (PASS == 0 || (k3 & hm) == pfx) atomicAdd(&h[wv][(k3 >> shift) & 255], 1u);
  }
  __syncthreads();
  unsigned c = h[0][tid] + h[1][tid] + h[2][tid] + h[3][tid];
  if (c) atomicAdd(&ghist[((size_t)PASS * NE + e) * 256 + tid], c);
}

// ---------------- Kernel 3: tie collection (+ final pick, writes state) -----------
__global__ __launch_bounds__(256)
void k_ties(const float* __restrict__ probsT, const unsigned* __restrict__ ghist,
            uint2* __restrict__ state, unsigned* __restrict__ tiecnt,
            int* __restrict__ tiebuf) {
  __shared__ unsigned res[2];
  const int tid = threadIdx.x;
  const int e = blockIdx.x >> 4;
  const int seg = blockIdx.x & (SEG - 1);

  unsigned pfx = 0, r = KSEL;
#pragma unroll
  for (int p = 0; p < 4; ++p) {
    unsigned b, rn;
    pick_scan(ghist + ((size_t)p * NE + e) * 256, r, b, rn, res);
    pfx |= b << (24 - 8 * p);
    r = rn;
  }
  if (tid == 0 && seg == 0) state[e] = make_uint2(pfx, r);

  const float* col = probsT + (size_t)e * GS + seg * SEGLEN;
  for (int i = 0; i < SEGLEN / 256; ++i) {
    int t = i * 256 + tid;
    if (__float_as_uint(col[t]) == pfx) {
      unsigned p = atomicAdd(&tiecnt[e], 1u);
      if (p < 1024u) tiebuf[e * 1024 + p] = seg * SEGLEN + t;
    }
  }
}

// ---------------- Kernel 4: cut index = r-th smallest tie index -------------------
__global__ __launch_bounds__(256)
void k_cut(const uint2* __restrict__ state, const unsigned* __restrict__ tiecnt,
           const int* __restrict__ tiebuf, int* __restrict__ cut) {
  __shared__ int sl[1024];
  const int e = blockIdx.x, tid = threadIdx.x;
  const int cnt = (int)min(tiecnt[e], 1024u);
  const int r = (int)state[e].y;
  for (int i = tid; i < cnt; i += 256) sl[i] = tiebuf[e * 1024 + i];
  __syncthreads();
  if (r > cnt) { if (tid == 0) cut[e] = 0x7FFFFFFF; return; }
  for (int i = tid; i < cnt; i += 256) {
    int v = sl[i], rank = 0;
    for (int j = 0; j < cnt; ++j) rank += (sl[j] < v);
    if (rank == r - 1) cut[e] = v;
  }
}

// ---------------- Kernel 5: dense mask scatter + loss -----------------------------
__global__ __launch_bounds__(256)
void k_scatter(const float* __restrict__ probsT, const uint2* __restrict__ state,
               const int* __restrict__ cut, float* __restrict__ out) {
  const int gid = blockIdx.x * 256 + threadIdx.x;
  const int base = gid * 4;
  const int e = base >> 15;
  const int t = base & (GS - 1);
  float4 p = *(const float4*)(probsT + (size_t)base);
  const unsigned T = state[e].x;
  const int ct = cut[e];
  float pv[4] = {p.x, p.y, p.z, p.w};
  float mk[4], wt[4];
#pragma unroll
  for (int c = 0; c < 4; ++c) {
    unsigned key = __float_as_uint(pv[c]);
    bool sel = (key > T) || (key == T && (t + c) <= ct);
    mk[c] = sel ? 1.0f : 0.0f;
    wt[c] = sel ? pv[c] : 0.0f;
  }
  *(float4*)(out + (size_t)base) = make_float4(mk[0], mk[1], mk[2], mk[3]);
  *(float4*)(out + (size_t)MASK_ELEMS + base) = make_float4(wt[0], wt[1], wt[2], wt[3]);
  if (gid == 0) out[2 * (size_t)MASK_ELEMS] = 0.0f;
}

extern "C" void kernel_launch(void* const* d_in, const int* in_sizes, int n_in,
                              void* d_out, int out_size, void* d_ws, size_t ws_size,
                              hipStream_t stream) {
  const float* x    = (const float*)d_in[0];
  const float* gw   = (const float*)d_in[1];
  const float* gb   = (const float*)d_in[2];
  const float* temp = (const float*)d_in[3];

  float* probsT    = (float*)d_ws;
  unsigned* ghist  = (unsigned*)((char*)d_ws + (size_t)MASK_ELEMS * 4);
  unsigned* tiecnt = ghist + 4 * NE * 256;
  uint2* state     = (uint2*)(tiecnt + NE);
  int* cutp        = (int*)(state + NE);
  int* tiebuf      = cutp + NE;

  hipMemsetAsync(ghist, 0, (4 * NE * 256 + NE) * sizeof(unsigned), stream);
  k_gemm_softmax<<<GS / 64, 256, 0, stream>>>(x, gw, gb, temp, probsT);
  k_hist<0><<<NE * SEG, 256, 0, stream>>>(probsT, ghist);
  k_hist<1><<<NE * SEG, 256, 0, stream>>>(probsT, ghist);
  k_hist<2><<<NE * SEG, 256, 0, stream>>>(probsT, ghist);
  k_hist<3><<<NE * SEG, 256, 0, stream>>>(probsT, ghist);
  k_ties<<<NE * SEG, 256, 0, stream>>>(probsT, ghist, state, tiecnt, tiebuf);
  k_cut<<<NE, 256, 0, stream>>>(state, tiecnt, tiebuf, cutp);
  k_scatter<<<MASK_ELEMS / 1024, 256, 0, stream>>>(probsT, state, cutp, (float*)d_out);
}